// Round 1
// baseline (995.496 us; speedup 1.0000x reference)
//
#include <hip/hip_runtime.h>

#define B_ 4
#define C_ 128
#define H_ 128
#define W_ 128
#define K_ 9
#define CK 1152   // C_ * K_
#define TP 8      // positions along W per block

// ---------------- prep: transpose weights [O][C*9] -> [C*9][O] ----------------
__global__ __launch_bounds__(256) void prep_weights(const float* __restrict__ w1,
                                                    const float* __restrict__ w2,
                                                    float* __restrict__ w1t,
                                                    float* __restrict__ w2t) {
    int i = blockIdx.x * 256 + threadIdx.x;
    const int n = C_ * CK;
    if (i < n) {
        int o = i / CK, ck = i % CK;
        w1t[ck * C_ + o] = w1[i];
    } else if (i < 2 * n) {
        int j = i - n;
        int o = j / CK, ck = j % CK;
        w2t[ck * C_ + o] = w2[j];
    }
}

// ---------------- kernel 1: deformable conv + BN1 + ReLU ----------------
__global__ __launch_bounds__(256) void deform_k(const float* __restrict__ x,
                                                const float* __restrict__ off,
                                                const float* __restrict__ w1t,
                                                const float* __restrict__ g,
                                                const float* __restrict__ bb,
                                                const float* __restrict__ mn,
                                                const float* __restrict__ vr,
                                                float* __restrict__ out1) {
    int blk = blockIdx.x;
    int wt = blk & 15;            // W_/TP = 16 tiles
    int h  = (blk >> 4) & 127;
    int b  = blk >> 11;
    int w0 = wt * TP;

    __shared__ float val[CK * TP];     // [ck][p]  36.9 KB
    __shared__ float spy[TP * K_];
    __shared__ float spx[TP * K_];

    int tid = threadIdx.x;

    // sample coordinates for 8 positions x 9 taps
    if (tid < TP * K_) {
        int p = tid / K_, k = tid % K_;
        int ww = w0 + p;
        int obase = ((b * 18 + 2 * k) * H_ + h) * W_ + ww;
        float dy = off[obase];
        float dx = off[obase + H_ * W_];
        spy[tid] = (float)(h + k / 3 - 1) + dy;
        spx[tid] = (float)(ww + k % 3 - 1) + dx;
    }
    __syncthreads();

    // gather: bilinear, zero-padding semantics
    const float* xb = x + (size_t)b * C_ * H_ * W_;
    for (int i = tid; i < CK * TP; i += 256) {
        int p = i & 7;
        int ck = i >> 3;
        int c = ck / 9;
        int k = ck - c * 9;
        float py = spy[p * 9 + k];
        float px = spx[p * 9 + k];
        float y0f = floorf(py), x0f = floorf(px);
        int y0 = (int)y0f, x0 = (int)x0f;
        float wy1 = py - y0f, wx1 = px - x0f;
        float wy0 = 1.f - wy1, wx0 = 1.f - wx1;
        int y1 = y0 + 1, x1 = x0 + 1;
        const float* xc = xb + c * H_ * W_;
        bool vy0 = (unsigned)y0 < (unsigned)H_;
        bool vy1 = (unsigned)y1 < (unsigned)H_;
        bool vx0 = (unsigned)x0 < (unsigned)W_;
        bool vx1 = (unsigned)x1 < (unsigned)W_;
        float v00 = (vy0 && vx0) ? xc[y0 * W_ + x0] : 0.f;
        float v01 = (vy0 && vx1) ? xc[y0 * W_ + x1] : 0.f;
        float v10 = (vy1 && vx0) ? xc[y1 * W_ + x0] : 0.f;
        float v11 = (vy1 && vx1) ? xc[y1 * W_ + x1] : 0.f;
        val[ck * 8 + p] = wy0 * (wx0 * v00 + wx1 * v01) + wy1 * (wx0 * v10 + wx1 * v11);
    }
    __syncthreads();

    // GEMM phase: each thread = 1 out channel x 4 positions
    int o = tid & 127;
    int pg = tid >> 7;   // 0 or 1
    float ax = 0.f, ay = 0.f, az = 0.f, aw = 0.f;
    const float* wp = w1t + o;
    for (int ck = 0; ck < CK; ++ck) {
        float wv = wp[ck * C_];
        float4 vv = *reinterpret_cast<const float4*>(&val[ck * 8 + pg * 4]);
        ax += vv.x * wv;
        ay += vv.y * wv;
        az += vv.z * wv;
        aw += vv.w * wv;
    }

    float inv = g[o] * rsqrtf(vr[o] + 1e-5f);
    float sh = bb[o] - mn[o] * inv;
    __syncthreads();
    val[o * 8 + pg * 4 + 0] = fmaxf(ax * inv + sh, 0.f);
    val[o * 8 + pg * 4 + 1] = fmaxf(ay * inv + sh, 0.f);
    val[o * 8 + pg * 4 + 2] = fmaxf(az * inv + sh, 0.f);
    val[o * 8 + pg * 4 + 3] = fmaxf(aw * inv + sh, 0.f);
    __syncthreads();

    for (int j = tid; j < C_ * TP; j += 256) {
        int oo = j >> 3, p = j & 7;
        out1[((b * C_ + oo) * H_ + h) * W_ + w0 + p] = val[j];
    }
}

// ---------------- kernel 2: dense 3x3 conv + BN2 + residual + ReLU ----------------
__global__ __launch_bounds__(256) void conv2_k(const float* __restrict__ in1,
                                               const float* __restrict__ x,
                                               const float* __restrict__ w2t,
                                               const float* __restrict__ g,
                                               const float* __restrict__ bb,
                                               const float* __restrict__ mn,
                                               const float* __restrict__ vr,
                                               float* __restrict__ out) {
    int blk = blockIdx.x;
    int wt = blk & 15;
    int h  = (blk >> 4) & 127;
    int b  = blk >> 11;
    int w0 = wt * TP;

    __shared__ float tile[C_ * 3 * 10];   // [c][row r=0..2][col 0..9] = cols w0-1 .. w0+8

    int tid = threadIdx.x;
    for (int i = tid; i < C_ * 30; i += 256) {
        int c = i / 30, rem = i % 30;
        int r = rem / 10, j = rem % 10;
        int hy = h + r - 1, wx = w0 + j - 1;
        float vv = 0.f;
        if (hy >= 0 && hy < H_ && wx >= 0 && wx < W_)
            vv = in1[((b * C_ + c) * H_ + hy) * W_ + wx];
        tile[i] = vv;
    }
    __syncthreads();

    int o = tid & 127;
    int pg = tid >> 7;
    float a0 = 0.f, a1 = 0.f, a2 = 0.f, a3 = 0.f;
    const float* wp = w2t + o;
    for (int ci = 0; ci < C_ * 3; ++ci) {   // ci = c*3 + r
        const float* trow = &tile[ci * 10 + pg * 4];
        float t0 = trow[0], t1 = trow[1], t2 = trow[2];
        float t3 = trow[3], t4 = trow[4], t5 = trow[5];
        float wv0 = wp[(ci * 3 + 0) * C_];
        float wv1 = wp[(ci * 3 + 1) * C_];
        float wv2 = wp[(ci * 3 + 2) * C_];
        a0 += t0 * wv0 + t1 * wv1 + t2 * wv2;
        a1 += t1 * wv0 + t2 * wv1 + t3 * wv2;
        a2 += t2 * wv0 + t3 * wv1 + t4 * wv2;
        a3 += t3 * wv0 + t4 * wv1 + t5 * wv2;
    }

    float inv = g[o] * rsqrtf(vr[o] + 1e-5f);
    float sh = bb[o] - mn[o] * inv;
    __syncthreads();
    tile[o * 8 + pg * 4 + 0] = a0 * inv + sh;
    tile[o * 8 + pg * 4 + 1] = a1 * inv + sh;
    tile[o * 8 + pg * 4 + 2] = a2 * inv + sh;
    tile[o * 8 + pg * 4 + 3] = a3 * inv + sh;
    __syncthreads();

    for (int j = tid; j < C_ * TP; j += 256) {
        int oo = j >> 3, p = j & 7;
        int idx = ((b * C_ + oo) * H_ + h) * W_ + w0 + p;
        out[idx] = fmaxf(tile[j] + x[idx], 0.f);
    }
}

extern "C" void kernel_launch(void* const* d_in, const int* in_sizes, int n_in,
                              void* d_out, int out_size, void* d_ws, size_t ws_size,
                              hipStream_t stream) {
    const float* x      = (const float*)d_in[0];
    const float* offset = (const float*)d_in[1];
    const float* w1     = (const float*)d_in[2];
    const float* bn1g   = (const float*)d_in[3];
    const float* bn1b   = (const float*)d_in[4];
    const float* bn1m   = (const float*)d_in[5];
    const float* bn1v   = (const float*)d_in[6];
    const float* w2     = (const float*)d_in[7];
    const float* bn2g   = (const float*)d_in[8];
    const float* bn2b   = (const float*)d_in[9];
    const float* bn2m   = (const float*)d_in[10];
    const float* bn2v   = (const float*)d_in[11];
    float* out = (float*)d_out;

    float* ws   = (float*)d_ws;
    float* w1t  = ws;                        // 147456 floats
    float* w2t  = ws + C_ * CK;              // 147456 floats
    float* inter = ws + 2 * C_ * CK;         // 8388608 floats (33.5 MB)

    const int nblocks = B_ * H_ * (W_ / TP); // 8192

    prep_weights<<<(2 * C_ * CK + 255) / 256, 256, 0, stream>>>(w1, w2, w1t, w2t);
    deform_k<<<nblocks, 256, 0, stream>>>(x, offset, w1t, bn1g, bn1b, bn1m, bn1v, inter);
    conv2_k<<<nblocks, 256, 0, stream>>>(inter, x, w2t, bn2g, bn2b, bn2m, bn2v, out);
}

// Round 2
// 135.905 us; speedup vs baseline: 7.3249x; 7.3249x over previous
//
#include <hip/hip_runtime.h>
#include <stdint.h>

#define B_ 4
#define C_ 128
#define H_ 128
#define W_ 128
#define HW 16384

typedef short short8 __attribute__((ext_vector_type(8)));
typedef float f32x4 __attribute__((ext_vector_type(4)));

__device__ __forceinline__ unsigned pack_bf16(float lo, float hi) {
    unsigned ul = __float_as_uint(lo);
    unsigned uh = __float_as_uint(hi);
    ul = (ul + 0x7fffu + ((ul >> 16) & 1u)) >> 16;
    uh = (uh + 0x7fffu + ((uh >> 16) & 1u)) & 0xffff0000u;
    return uh | ul;
}

__device__ __forceinline__ void gll16(const void* g, void* l) {
    __builtin_amdgcn_global_load_lds((const unsigned int*)g, (unsigned int*)l, 16, 0, 0);
}

// ---------------- prep: weights -> bf16, K reordered to tap*128+c ----------------
__global__ __launch_bounds__(256) void prep_w(const float* __restrict__ w1,
                                              const float* __restrict__ w2,
                                              unsigned short* __restrict__ w1t,
                                              unsigned short* __restrict__ w2t) {
    int i = blockIdx.x * 256 + threadIdx.x;
    const float* src = w1;
    unsigned short* dst = w1t;
    int j = i;
    if (i >= 147456) { j = i - 147456; src = w2; dst = w2t; }
    int o = j / 1152, rem = j % 1152;
    int c = rem / 9, tap = rem % 9;
    unsigned u = __float_as_uint(src[j]);
    u = (u + 0x7fffu + ((u >> 16) & 1u)) >> 16;
    dst[o * 1152 + tap * 128 + c] = (unsigned short)u;
}

__global__ __launch_bounds__(256) void bn_prep(const float* g1, const float* b1, const float* m1, const float* v1,
                                               const float* g2, const float* b2, const float* m2, const float* v2,
                                               float* inv1, float* sh1, float* inv2, float* sh2) {
    int t = threadIdx.x;
    if (t < 128) {
        float iv = g1[t] * rsqrtf(v1[t] + 1e-5f);
        inv1[t] = iv; sh1[t] = b1[t] - m1[t] * iv;
    } else {
        int u = t - 128;
        float iv = g2[u] * rsqrtf(v2[u] + 1e-5f);
        inv2[u] = iv; sh2[u] = b2[u] - m2[u] * iv;
    }
}

// ---------------- x NCHW fp32 -> NHWC bf16 (32x32 tiles) ----------------
__global__ __launch_bounds__(256) void nhwc_k(const float* __restrict__ x,
                                              unsigned short* __restrict__ xh) {
    __shared__ unsigned short tile[32][36];
    int blk = blockIdx.x;
    int wt = blk & 3, ct = (blk >> 2) & 3, h = (blk >> 4) & 127, b = blk >> 11;
    int t = threadIdx.x;
    int c = t >> 3, seg = t & 7;
    const float* srcp = x + ((size_t)((b * 128 + ct * 32 + c) * 128 + h) * 128) + wt * 32 + seg * 4;
    float4 v = *(const float4*)srcp;
    uint2 pk;
    pk.x = pack_bf16(v.x, v.y);
    pk.y = pack_bf16(v.z, v.w);
    *(uint2*)&tile[c][seg * 4] = pk;
    __syncthreads();
    int w = t >> 3, s2 = t & 7;
    unsigned a0 = tile[s2 * 4 + 0][w];
    unsigned a1 = tile[s2 * 4 + 1][w];
    unsigned a2 = tile[s2 * 4 + 2][w];
    unsigned a3 = tile[s2 * 4 + 3][w];
    uint2 o;
    o.x = (a1 << 16) | a0;
    o.y = (a3 << 16) | a2;
    *(uint2*)(xh + ((size_t)((b * 128 + h) * 128 + wt * 32 + w) * 128) + ct * 32 + s2 * 4) = o;
}

__global__ __launch_bounds__(256) void zero_k(uint4* __restrict__ p, int nchunks) {
    int i = blockIdx.x * 256 + threadIdx.x;
    int stride = gridDim.x * 256;
    uint4 z = {0u, 0u, 0u, 0u};
    for (; i < nchunks; i += stride) p[i] = z;
}

// ---------------- GEMM1: fused deformable gather + MFMA + BN1 + ReLU -> halo NHWC bf16 ----------------
__global__ __launch_bounds__(256, 2) void gemm1_k(
    const unsigned short* __restrict__ xh,
    const float* __restrict__ off,
    const unsigned short* __restrict__ w1t,
    const float* __restrict__ inv1,
    const float* __restrict__ sh1,
    unsigned short* __restrict__ out1p) {
    __shared__ __align__(16) char lds[34816 + 32768];
    char* ldsv = lds;          // gathered val tile [128 pos][136] bf16 (padded rows)
    char* ldsw = lds + 34816;  // weight tile [128 o][16 chunks] swizzled

    int bid = blockIdx.x;
    int swz = ((bid & 7) << 6) | (bid >> 3);
    int h = swz & 127, b = swz >> 7;
    int tid = threadIdx.x;
    int lane = tid & 63, wv = tid >> 6;
    int lr = lane & 15, lq = lane >> 4;
    int ob = (wv & 1) << 6, pb = (wv >> 1) << 6;

    f32x4 acc[4][4] = {};

    int p = tid >> 1;
    int chalf = (tid & 1) << 6;

    for (int tap = 0; tap < 9; ++tap) {
        // ---- bilinear gather of 128 channels for position p, tap ----
        {
            int kh = tap / 3 - 1, kw = tap % 3 - 1;
            int oidx = ((b * 18 + 2 * tap) * H_ + h) * W_ + p;
            float dy = off[oidx];
            float dx = off[oidx + HW];
            float py = (float)(h + kh) + dy;
            float px = (float)(p + kw) + dx;
            float y0f = floorf(py), x0f = floorf(px);
            int y0 = (int)y0f, x0 = (int)x0f;
            float wy1 = py - y0f, wx1 = px - x0f;
            float wy0 = 1.f - wy1, wx0 = 1.f - wx1;
            int y1 = y0 + 1, x1 = x0 + 1;
            float w00 = ((unsigned)y0 < 128u && (unsigned)x0 < 128u) ? wy0 * wx0 : 0.f;
            float w01 = ((unsigned)y0 < 128u && (unsigned)x1 < 128u) ? wy0 * wx1 : 0.f;
            float w10 = ((unsigned)y1 < 128u && (unsigned)x0 < 128u) ? wy1 * wx0 : 0.f;
            float w11 = ((unsigned)y1 < 128u && (unsigned)x1 < 128u) ? wy1 * wx1 : 0.f;
            int y0c = min(max(y0, 0), 127), y1c = min(max(y1, 0), 127);
            int x0c = min(max(x0, 0), 127), x1c = min(max(x1, 0), 127);
            const unsigned short* r00 = xh + ((size_t)((b * H_ + y0c) * W_ + x0c) << 7) + chalf;
            const unsigned short* r01 = xh + ((size_t)((b * H_ + y0c) * W_ + x1c) << 7) + chalf;
            const unsigned short* r10 = xh + ((size_t)((b * H_ + y1c) * W_ + x0c) << 7) + chalf;
            const unsigned short* r11 = xh + ((size_t)((b * H_ + y1c) * W_ + x1c) << 7) + chalf;
            char* dst = ldsv + p * 272 + chalf * 2;
            #pragma unroll
            for (int ci = 0; ci < 8; ++ci) {
                uint4 q00 = *(const uint4*)(r00 + ci * 8);
                uint4 q01 = *(const uint4*)(r01 + ci * 8);
                uint4 q10 = *(const uint4*)(r10 + ci * 8);
                uint4 q11 = *(const uint4*)(r11 + ci * 8);
                const unsigned* a = (const unsigned*)&q00;
                const unsigned* bq = (const unsigned*)&q01;
                const unsigned* cq = (const unsigned*)&q10;
                const unsigned* dq = (const unsigned*)&q11;
                uint4 st;
                unsigned* so = (unsigned*)&st;
                #pragma unroll
                for (int e = 0; e < 4; ++e) {
                    float lo = w00 * __uint_as_float(a[e] << 16)
                             + w01 * __uint_as_float(bq[e] << 16)
                             + w10 * __uint_as_float(cq[e] << 16)
                             + w11 * __uint_as_float(dq[e] << 16);
                    float hi = w00 * __uint_as_float(a[e] & 0xffff0000u)
                             + w01 * __uint_as_float(bq[e] & 0xffff0000u)
                             + w10 * __uint_as_float(cq[e] & 0xffff0000u)
                             + w11 * __uint_as_float(dq[e] & 0xffff0000u);
                    so[e] = pack_bf16(lo, hi);
                }
                *(uint4*)(dst + ci * 16) = st;
            }
        }
        // ---- stage weight tile [128][128] for this tap (swizzled source) ----
        #pragma unroll
        for (int it = 0; it < 8; ++it) {
            int cb = it * 256 + wv * 64;
            int ci = cb + lane;
            int o = ci >> 4, q = ci & 15;
            gll16((const char*)w1t + o * 2304 + tap * 256 + ((q ^ (o & 7)) << 4), ldsw + cb * 16);
        }
        __syncthreads();
        // ---- 4 K-steps of 32 ----
        #pragma unroll
        for (int c0s = 0; c0s < 4; ++c0s) {
            short8 af[4], bfr[4];
            int qn = lq + c0s * 4;
            #pragma unroll
            for (int i = 0; i < 4; ++i) {
                int row = ob + i * 16 + lr;
                af[i] = *(const short8*)(ldsw + row * 256 + ((qn ^ (row & 7)) << 4));
            }
            #pragma unroll
            for (int j = 0; j < 4; ++j) {
                int prow = pb + j * 16 + lr;
                bfr[j] = *(const short8*)(ldsv + prow * 272 + c0s * 64 + lq * 16);
            }
            #pragma unroll
            for (int i = 0; i < 4; ++i)
                #pragma unroll
                for (int j = 0; j < 4; ++j)
                    acc[i][j] = __builtin_amdgcn_mfma_f32_16x16x32_bf16(af[i], bfr[j], acc[i][j], 0, 0, 0);
        }
        __syncthreads();
    }

    // ---- epilogue: BN1 + ReLU -> bf16 -> swizzled LDS [pos][o] -> coalesced NHWC store ----
    float4 iv[4], sv[4];
    #pragma unroll
    for (int i = 0; i < 4; ++i) {
        int o0 = ob + i * 16 + lq * 4;
        iv[i] = *(const float4*)(inv1 + o0);
        sv[i] = *(const float4*)(sh1 + o0);
    }
    #pragma unroll
    for (int i = 0; i < 4; ++i) {
        int o0 = ob + i * 16 + lq * 4;
        #pragma unroll
        for (int j = 0; j < 4; ++j) {
            int pos = pb + j * 16 + lr;
            f32x4 a = acc[i][j];
            float v0 = fmaxf(fmaf(a[0], iv[i].x, sv[i].x), 0.f);
            float v1 = fmaxf(fmaf(a[1], iv[i].y, sv[i].y), 0.f);
            float v2 = fmaxf(fmaf(a[2], iv[i].z, sv[i].z), 0.f);
            float v3 = fmaxf(fmaf(a[3], iv[i].w, sv[i].w), 0.f);
            uint2 pk;
            pk.x = pack_bf16(v0, v1);
            pk.y = pack_bf16(v2, v3);
            *(uint2*)(ldsw + pos * 256 + ((o0 * 2) ^ ((pos & 7) << 4))) = pk;
        }
    }
    __syncthreads();
    char* dstg = (char*)out1p + ((size_t)((b * 130 + h + 1) * 130 + 1)) * 256;
    #pragma unroll
    for (int it = 0; it < 8; ++it) {
        int ci = it * 256 + tid;
        int pos = ci >> 4, q = ci & 15;
        uint4 v = *(const uint4*)(ldsw + pos * 256 + ((q << 4) ^ ((pos & 7) << 4)));
        *(uint4*)(dstg + ci * 16) = v;
    }
}

// ---------------- GEMM2: dense 3x3 conv from halo NHWC + BN2 + residual + ReLU -> NCHW fp32 ----------------
__global__ __launch_bounds__(256, 2) void gemm2_k(
    const unsigned short* __restrict__ out1p,
    const unsigned short* __restrict__ w2t,
    const float* __restrict__ x,
    const float* __restrict__ inv2,
    const float* __restrict__ sh2,
    float* __restrict__ outp) {
    __shared__ __align__(16) char lds[33792 + 32768];
    char* ldsS = lds;          // input row tile [130][16 chunks] swizzled
    char* ldsw = lds + 33792;  // weight tile [128][16 chunks] swizzled

    int bid = blockIdx.x;
    int swz = ((bid & 7) << 6) | (bid >> 3);
    int h = swz & 127, b = swz >> 7;
    int tid = threadIdx.x;
    int lane = tid & 63, wv = tid >> 6;
    int lr = lane & 15, lq = lane >> 4;
    int ob = (wv & 1) << 6, pb = (wv >> 1) << 6;

    f32x4 acc[4][4] = {};

    for (int kh = 0; kh < 3; ++kh) {
        const char* srow = (const char*)out1p + (size_t)((b * 130 + h + kh) * 130) * 256;
        for (int it = 0; it < 9; ++it) {
            int cb = it * 256 + wv * 64;
            int ci = cb + lane;
            if (ci < 2080) {
                int r = ci >> 4, q = ci & 15;
                gll16(srow + r * 256 + ((q ^ (r & 7)) << 4), ldsS + cb * 16);
            }
        }
        for (int kw = 0; kw < 3; ++kw) {
            int tap = kh * 3 + kw;
            #pragma unroll
            for (int it = 0; it < 8; ++it) {
                int cb = it * 256 + wv * 64;
                int ci = cb + lane;
                int o = ci >> 4, q = ci & 15;
                gll16((const char*)w2t + o * 2304 + tap * 256 + ((q ^ (o & 7)) << 4), ldsw + cb * 16);
            }
            __syncthreads();
            #pragma unroll
            for (int c0s = 0; c0s < 4; ++c0s) {
                short8 av[4], bw[4];
                int qn = lq + c0s * 4;
                #pragma unroll
                for (int i = 0; i < 4; ++i) {
                    int prow = pb + i * 16 + lr + kw;
                    av[i] = *(const short8*)(ldsS + prow * 256 + ((qn ^ (prow & 7)) << 4));
                }
                #pragma unroll
                for (int j = 0; j < 4; ++j) {
                    int orow = ob + j * 16 + lr;
                    bw[j] = *(const short8*)(ldsw + orow * 256 + ((qn ^ (orow & 7)) << 4));
                }
                #pragma unroll
                for (int i = 0; i < 4; ++i)
                    #pragma unroll
                    for (int j = 0; j < 4; ++j)
                        acc[i][j] = __builtin_amdgcn_mfma_f32_16x16x32_bf16(av[i], bw[j], acc[i][j], 0, 0, 0);
            }
            __syncthreads();
        }
    }

    float iv2[4], sv2[4];
    #pragma unroll
    for (int j = 0; j < 4; ++j) {
        int o = ob + j * 16 + lr;
        iv2[j] = inv2[o];
        sv2[j] = sh2[o];
    }
    #pragma unroll
    for (int j = 0; j < 4; ++j) {
        int o = ob + j * 16 + lr;
        #pragma unroll
        for (int i = 0; i < 4; ++i) {
            int pos0 = pb + i * 16 + lq * 4;
            size_t base = ((size_t)(b * C_ + o) * H_ + h) * W_ + pos0;
            float4 rx = *(const float4*)(x + base);
            f32x4 a = acc[i][j];
            float4 ov;
            ov.x = fmaxf(fmaf(a[0], iv2[j], sv2[j]) + rx.x, 0.f);
            ov.y = fmaxf(fmaf(a[1], iv2[j], sv2[j]) + rx.y, 0.f);
            ov.z = fmaxf(fmaf(a[2], iv2[j], sv2[j]) + rx.z, 0.f);
            ov.w = fmaxf(fmaf(a[3], iv2[j], sv2[j]) + rx.w, 0.f);
            *(float4*)(outp + base) = ov;
        }
    }
}

extern "C" void kernel_launch(void* const* d_in, const int* in_sizes, int n_in,
                              void* d_out, int out_size, void* d_ws, size_t ws_size,
                              hipStream_t stream) {
    const float* x   = (const float*)d_in[0];
    const float* off = (const float*)d_in[1];
    const float* w1  = (const float*)d_in[2];
    const float* g1  = (const float*)d_in[3];
    const float* b1  = (const float*)d_in[4];
    const float* m1  = (const float*)d_in[5];
    const float* v1  = (const float*)d_in[6];
    const float* w2  = (const float*)d_in[7];
    const float* g2  = (const float*)d_in[8];
    const float* b2  = (const float*)d_in[9];
    const float* m2  = (const float*)d_in[10];
    const float* v2  = (const float*)d_in[11];
    float* outp = (float*)d_out;

    char* ws = (char*)d_ws;
    unsigned short* w1t = (unsigned short*)(ws);
    unsigned short* w2t = (unsigned short*)(ws + 294912);
    float* inv1 = (float*)(ws + 589824);
    float* sh1  = (float*)(ws + 590336);
    float* inv2 = (float*)(ws + 590848);
    float* sh2  = (float*)(ws + 591360);
    unsigned short* xh  = (unsigned short*)(ws + 591872);
    unsigned short* o1p = (unsigned short*)(ws + 17369088);

    prep_w<<<1152, 256, 0, stream>>>(w1, w2, w1t, w2t);
    bn_prep<<<1, 256, 0, stream>>>(g1, b1, m1, v1, g2, b2, m2, v2, inv1, sh1, inv2, sh2);
    nhwc_k<<<8192, 256, 0, stream>>>(x, xh);
    zero_k<<<2048, 256, 0, stream>>>((uint4*)o1p, 17305600 / 16);
    gemm1_k<<<512, 256, 0, stream>>>(xh, off, w1t, inv1, sh1, o1p);
    gemm2_k<<<512, 256, 0, stream>>>(o1p, w2t, x, inv2, sh2, outp);
}

// Round 3
// 113.041 us; speedup vs baseline: 8.8065x; 1.2023x over previous
//
#include <hip/hip_runtime.h>
#include <stdint.h>

#define B_ 4
#define C_ 128
#define H_ 128
#define W_ 128
#define HW 16384

typedef short short8 __attribute__((ext_vector_type(8)));
typedef float f32x4 __attribute__((ext_vector_type(4)));

__device__ __forceinline__ unsigned pack_bf16(float lo, float hi) {
    unsigned ul = __float_as_uint(lo);
    unsigned uh = __float_as_uint(hi);
    ul = (ul + 0x7fffu + ((ul >> 16) & 1u)) >> 16;
    uh = (uh + 0x7fffu + ((uh >> 16) & 1u)) & 0xffff0000u;
    return uh | ul;
}

__device__ __forceinline__ unsigned cvtpk(float lo, float hi) {
    unsigned r;
    asm("v_cvt_pk_bf16_f32 %0, %1, %2" : "=v"(r) : "v"(lo), "v"(hi));
    return r;
}

__device__ __forceinline__ unsigned blend1(unsigned a, unsigned bq, unsigned cq, unsigned dq,
                                           float w0, float w1, float w2, float w3) {
    float lo = w0 * __uint_as_float(a << 16) + w1 * __uint_as_float(bq << 16)
             + w2 * __uint_as_float(cq << 16) + w3 * __uint_as_float(dq << 16);
    float hi = w0 * __uint_as_float(a & 0xffff0000u) + w1 * __uint_as_float(bq & 0xffff0000u)
             + w2 * __uint_as_float(cq & 0xffff0000u) + w3 * __uint_as_float(dq & 0xffff0000u);
    return cvtpk(lo, hi);
}

__device__ __forceinline__ void gll16(const void* g, void* l) {
    __builtin_amdgcn_global_load_lds((const unsigned int*)g, (unsigned int*)l, 16, 0, 0);
}

// ---------------- prep: weights -> bf16, K reordered to tap*128+c ----------------
__global__ __launch_bounds__(256) void prep_w(const float* __restrict__ w1,
                                              const float* __restrict__ w2,
                                              unsigned short* __restrict__ w1t,
                                              unsigned short* __restrict__ w2t) {
    int i = blockIdx.x * 256 + threadIdx.x;
    const float* src = w1;
    unsigned short* dst = w1t;
    int j = i;
    if (i >= 147456) { j = i - 147456; src = w2; dst = w2t; }
    int o = j / 1152, rem = j % 1152;
    int c = rem / 9, tap = rem % 9;
    unsigned u = __float_as_uint(src[j]);
    u = (u + 0x7fffu + ((u >> 16) & 1u)) >> 16;
    dst[o * 1152 + tap * 128 + c] = (unsigned short)u;
}

__global__ __launch_bounds__(256) void bn_prep(const float* g1, const float* b1, const float* m1, const float* v1,
                                               const float* g2, const float* b2, const float* m2, const float* v2,
                                               float* inv1, float* sh1, float* inv2, float* sh2) {
    int t = threadIdx.x;
    if (t < 128) {
        float iv = g1[t] * rsqrtf(v1[t] + 1e-5f);
        inv1[t] = iv; sh1[t] = b1[t] - m1[t] * iv;
    } else {
        int u = t - 128;
        float iv = g2[u] * rsqrtf(v2[u] + 1e-5f);
        inv2[u] = iv; sh2[u] = b2[u] - m2[u] * iv;
    }
}

// ---------------- x NCHW fp32 -> NHWC bf16 (32x32 tiles) ----------------
__global__ __launch_bounds__(256) void nhwc_k(const float* __restrict__ x,
                                              unsigned short* __restrict__ xh) {
    __shared__ unsigned short tile[32][36];
    int blk = blockIdx.x;
    int wt = blk & 3, ct = (blk >> 2) & 3, h = (blk >> 4) & 127, b = blk >> 11;
    int t = threadIdx.x;
    int c = t >> 3, seg = t & 7;
    const float* srcp = x + ((size_t)((b * 128 + ct * 32 + c) * 128 + h) * 128) + wt * 32 + seg * 4;
    float4 v = *(const float4*)srcp;
    uint2 pk;
    pk.x = pack_bf16(v.x, v.y);
    pk.y = pack_bf16(v.z, v.w);
    *(uint2*)&tile[c][seg * 4] = pk;
    __syncthreads();
    int w = t >> 3, s2 = t & 7;
    unsigned a0 = tile[s2 * 4 + 0][w];
    unsigned a1 = tile[s2 * 4 + 1][w];
    unsigned a2 = tile[s2 * 4 + 2][w];
    unsigned a3 = tile[s2 * 4 + 3][w];
    uint2 o;
    o.x = (a1 << 16) | a0;
    o.y = (a3 << 16) | a2;
    *(uint2*)(xh + ((size_t)((b * 128 + h) * 128 + wt * 32 + w) * 128) + ct * 32 + s2 * 4) = o;
}

// ---------------- zero only the halo border of the intermediate buffer ----------------
__global__ __launch_bounds__(256) void border_k(unsigned short* __restrict__ o1p) {
    int i = blockIdx.x * 256 + threadIdx.x;   // 4 * 516 * 16 = 33024
    if (i >= 33024) return;
    int chunk = i & 15;
    int pos = i >> 4;
    int b = pos / 516;
    int r = pos % 516;
    int row, col;
    if (r < 130)      { row = 0;   col = r; }
    else if (r < 260) { row = 129; col = r - 130; }
    else { int j = r - 260; row = 1 + (j >> 1); col = (j & 1) * 129; }
    uint4 z = {0u, 0u, 0u, 0u};
    *(uint4*)((char*)o1p + (size_t)((b * 130 + row) * 130 + col) * 256 + chunk * 16) = z;
}

// ---------------- GEMM1: fused deformable gather + MFMA + BN1 + ReLU -> halo NHWC bf16 ----------------
__global__ __launch_bounds__(256, 2) void gemm1_k(
    const unsigned short* __restrict__ xh,
    const float* __restrict__ off,
    const unsigned short* __restrict__ w1t,
    const float* __restrict__ inv1,
    const float* __restrict__ sh1,
    unsigned short* __restrict__ out1p) {
    __shared__ __align__(16) char ldsw[32768];   // weight tile [128 o][16 chunks] swizzled
    __shared__ __align__(16) char ldsv[32768];   // 4 waves x wave-private [32 p][256B] swizzled

    int bid = blockIdx.x;
    int swz = ((bid & 7) << 6) | (bid >> 3);
    int h = swz & 127, b = swz >> 7;
    int tid = threadIdx.x;
    int lane = tid & 63, wv = tid >> 6;
    int lr = lane & 15, lq = lane >> 4;
    char* vpriv = ldsv + wv * 8192;
    int p0w = wv * 32;
    int pseli = lane >> 4;   // which of 4 positions within a chunk
    int seg = lane & 15;     // channel chunk (8 ch = 16B)

    f32x4 acc[8][2] = {};

#define META_ISSUE(c, buf, wgt) do { \
    int p_ = p0w + (c) * 4 + pseli; \
    float dy_ = off[dyBase + p_]; \
    float dx_ = off[dxBase + p_]; \
    float py_ = (float)(h + kh) + dy_; \
    float px_ = (float)(p_ + kw) + dx_; \
    float y0f_ = floorf(py_), x0f_ = floorf(px_); \
    int y0_ = (int)y0f_, x0_ = (int)x0f_; \
    float wy1_ = py_ - y0f_, wx1_ = px_ - x0f_; \
    float wy0_ = 1.f - wy1_, wx0_ = 1.f - wx1_; \
    int y1_ = y0_ + 1, x1_ = x0_ + 1; \
    wgt[0] = ((unsigned)y0_ < 128u && (unsigned)x0_ < 128u) ? wy0_ * wx0_ : 0.f; \
    wgt[1] = ((unsigned)y0_ < 128u && (unsigned)x1_ < 128u) ? wy0_ * wx1_ : 0.f; \
    wgt[2] = ((unsigned)y1_ < 128u && (unsigned)x0_ < 128u) ? wy1_ * wx0_ : 0.f; \
    wgt[3] = ((unsigned)y1_ < 128u && (unsigned)x1_ < 128u) ? wy1_ * wx1_ : 0.f; \
    int y0c_ = min(max(y0_, 0), 127), y1c_ = min(max(y1_, 0), 127); \
    int x0c_ = min(max(x0_, 0), 127), x1c_ = min(max(x1_, 0), 127); \
    const uint4* xq_ = (const uint4*)xh; \
    int r0_ = (b * H_ + y0c_) * W_; \
    int r1_ = (b * H_ + y1c_) * W_; \
    buf[0] = xq_[(size_t)(r0_ + x0c_) * 16 + seg]; \
    buf[1] = xq_[(size_t)(r0_ + x1c_) * 16 + seg]; \
    buf[2] = xq_[(size_t)(r1_ + x0c_) * 16 + seg]; \
    buf[3] = xq_[(size_t)(r1_ + x1c_) * 16 + seg]; \
} while (0)

#define BLEND_STORE(c, buf, wgt) do { \
    int pl_ = (c) * 4 + pseli; \
    uint4 st_; \
    st_.x = blend1(buf[0].x, buf[1].x, buf[2].x, buf[3].x, wgt[0], wgt[1], wgt[2], wgt[3]); \
    st_.y = blend1(buf[0].y, buf[1].y, buf[2].y, buf[3].y, wgt[0], wgt[1], wgt[2], wgt[3]); \
    st_.z = blend1(buf[0].z, buf[1].z, buf[2].z, buf[3].z, wgt[0], wgt[1], wgt[2], wgt[3]); \
    st_.w = blend1(buf[0].w, buf[1].w, buf[2].w, buf[3].w, wgt[0], wgt[1], wgt[2], wgt[3]); \
    *(uint4*)(vpriv + pl_ * 256 + ((seg ^ (pl_ & 7)) << 4)) = st_; \
} while (0)

    for (int tap = 0; tap < 9; ++tap) {
        __syncthreads();   // all waves done reading ldsw of previous tap
        // stage weight tile for this tap (linear LDS dest, inverse-swizzled source)
        #pragma unroll
        for (int it = 0; it < 8; ++it) {
            int ci = it * 256 + tid;
            int o = ci >> 4, q = ci & 15;
            gll16((const char*)w1t + o * 2304 + tap * 256 + ((q ^ (o & 7)) << 4), ldsw + ci * 16);
        }
        int kh = tap / 3 - 1, kw = tap % 3 - 1;
        int dyBase = ((b * 18 + 2 * tap) * H_ + h) * W_;
        int dxBase = dyBase + HW;

        // gather 32 positions: 8 chunks of 4 p, 2-deep register pipeline
        uint4 bufA[4], bufB[4];
        float wA[4], wB[4];
        META_ISSUE(0, bufA, wA);
        META_ISSUE(1, bufB, wB);
        #pragma unroll
        for (int c = 0; c < 8; c += 2) {
            BLEND_STORE(c, bufA, wA);
            if (c + 2 < 8) META_ISSUE(c + 2, bufA, wA);
            BLEND_STORE(c + 1, bufB, wB);
            if (c + 3 < 8) META_ISSUE(c + 3, bufB, wB);
        }

        __syncthreads();   // weight tile staged (syncthreads drains vmcnt)

        #pragma unroll
        for (int c0s = 0; c0s < 4; ++c0s) {
            short8 af[8], bfr[2];
            int qn = lq + c0s * 4;
            #pragma unroll
            for (int i = 0; i < 8; ++i) {
                int row = i * 16 + lr;
                af[i] = *(const short8*)(ldsw + row * 256 + ((qn ^ (row & 7)) << 4));
            }
            #pragma unroll
            for (int j = 0; j < 2; ++j) {
                int prow = j * 16 + lr;
                bfr[j] = *(const short8*)(vpriv + prow * 256 + ((qn ^ (prow & 7)) << 4));
            }
            #pragma unroll
            for (int i = 0; i < 8; ++i)
                #pragma unroll
                for (int j = 0; j < 2; ++j)
                    acc[i][j] = __builtin_amdgcn_mfma_f32_16x16x32_bf16(af[i], bfr[j], acc[i][j], 0, 0, 0);
        }
    }

#undef META_ISSUE
#undef BLEND_STORE

    // epilogue: BN1 + ReLU -> bf16, direct NHWC halo store (4 consecutive o per lane)
    #pragma unroll
    for (int i = 0; i < 8; ++i) {
        int o0 = i * 16 + lq * 4;
        float4 iv = *(const float4*)(inv1 + o0);
        float4 sv = *(const float4*)(sh1 + o0);
        #pragma unroll
        for (int j = 0; j < 2; ++j) {
            int p = p0w + j * 16 + lr;
            f32x4 a = acc[i][j];
            float v0 = fmaxf(fmaf(a[0], iv.x, sv.x), 0.f);
            float v1 = fmaxf(fmaf(a[1], iv.y, sv.y), 0.f);
            float v2 = fmaxf(fmaf(a[2], iv.z, sv.z), 0.f);
            float v3 = fmaxf(fmaf(a[3], iv.w, sv.w), 0.f);
            uint2 pk;
            pk.x = cvtpk(v0, v1);
            pk.y = cvtpk(v2, v3);
            size_t idx = (size_t)((b * 130 + h + 1) * 130 + 1 + p) * 128 + o0;
            *(uint2*)(out1p + idx) = pk;
        }
    }
}

// ---------------- GEMM2: dense 3x3 conv from halo NHWC + BN2 + residual + ReLU -> NCHW fp32 ----------------
__global__ __launch_bounds__(256, 2) void gemm2_k(
    const unsigned short* __restrict__ out1p,
    const unsigned short* __restrict__ w2t,
    const float* __restrict__ x,
    const float* __restrict__ inv2,
    const float* __restrict__ sh2,
    float* __restrict__ outp) {
    __shared__ __align__(16) char lds[33792 + 32768];
    char* ldsS = lds;          // input row tile [130][16 chunks] swizzled
    char* ldsw = lds + 33792;  // weight tile [128][16 chunks] swizzled

    int bid = blockIdx.x;
    int swz = ((bid & 7) << 6) | (bid >> 3);
    int h = swz & 127, b = swz >> 7;
    int tid = threadIdx.x;
    int lane = tid & 63, wv = tid >> 6;
    int lr = lane & 15, lq = lane >> 4;
    int ob = (wv & 1) << 6, pb = (wv >> 1) << 6;

    f32x4 acc[4][4] = {};

    for (int kh = 0; kh < 3; ++kh) {
        const char* srow = (const char*)out1p + (size_t)((b * 130 + h + kh) * 130) * 256;
        for (int it = 0; it < 9; ++it) {
            int cb = it * 256 + wv * 64;
            int ci = cb + lane;
            if (ci < 2080) {
                int r = ci >> 4, q = ci & 15;
                gll16(srow + r * 256 + ((q ^ (r & 7)) << 4), ldsS + cb * 16);
            }
        }
        for (int kw = 0; kw < 3; ++kw) {
            int tap = kh * 3 + kw;
            #pragma unroll
            for (int it = 0; it < 8; ++it) {
                int cb = it * 256 + wv * 64;
                int ci = cb + lane;
                int o = ci >> 4, q = ci & 15;
                gll16((const char*)w2t + o * 2304 + tap * 256 + ((q ^ (o & 7)) << 4), ldsw + cb * 16);
            }
            __syncthreads();
            #pragma unroll
            for (int c0s = 0; c0s < 4; ++c0s) {
                short8 av[4], bw[4];
                int qn = lq + c0s * 4;
                #pragma unroll
                for (int i = 0; i < 4; ++i) {
                    int prow = pb + i * 16 + lr + kw;
                    av[i] = *(const short8*)(ldsS + prow * 256 + ((qn ^ (prow & 7)) << 4));
                }
                #pragma unroll
                for (int j = 0; j < 4; ++j) {
                    int orow = ob + j * 16 + lr;
                    bw[j] = *(const short8*)(ldsw + orow * 256 + ((qn ^ (orow & 7)) << 4));
                }
                #pragma unroll
                for (int i = 0; i < 4; ++i)
                    #pragma unroll
                    for (int j = 0; j < 4; ++j)
                        acc[i][j] = __builtin_amdgcn_mfma_f32_16x16x32_bf16(av[i], bw[j], acc[i][j], 0, 0, 0);
            }
            __syncthreads();
        }
    }

    float iv2[4], sv2[4];
    #pragma unroll
    for (int j = 0; j < 4; ++j) {
        int o = ob + j * 16 + lr;
        iv2[j] = inv2[o];
        sv2[j] = sh2[o];
    }
    #pragma unroll
    for (int j = 0; j < 4; ++j) {
        int o = ob + j * 16 + lr;
        #pragma unroll
        for (int i = 0; i < 4; ++i) {
            int pos0 = pb + i * 16 + lq * 4;
            size_t base = ((size_t)(b * C_ + o) * H_ + h) * W_ + pos0;
            float4 rx = *(const float4*)(x + base);
            f32x4 a = acc[i][j];
            float4 ov;
            ov.x = fmaxf(fmaf(a[0], iv2[j], sv2[j]) + rx.x, 0.f);
            ov.y = fmaxf(fmaf(a[1], iv2[j], sv2[j]) + rx.y, 0.f);
            ov.z = fmaxf(fmaf(a[2], iv2[j], sv2[j]) + rx.z, 0.f);
            ov.w = fmaxf(fmaf(a[3], iv2[j], sv2[j]) + rx.w, 0.f);
            *(float4*)(outp + base) = ov;
        }
    }
}

extern "C" void kernel_launch(void* const* d_in, const int* in_sizes, int n_in,
                              void* d_out, int out_size, void* d_ws, size_t ws_size,
                              hipStream_t stream) {
    const float* x   = (const float*)d_in[0];
    const float* off = (const float*)d_in[1];
    const float* w1  = (const float*)d_in[2];
    const float* g1  = (const float*)d_in[3];
    const float* b1  = (const float*)d_in[4];
    const float* m1  = (const float*)d_in[5];
    const float* v1  = (const float*)d_in[6];
    const float* w2  = (const float*)d_in[7];
    const float* g2  = (const float*)d_in[8];
    const float* b2  = (const float*)d_in[9];
    const float* m2  = (const float*)d_in[10];
    const float* v2  = (const float*)d_in[11];
    float* outp = (float*)d_out;

    char* ws = (char*)d_ws;
    unsigned short* w1t = (unsigned short*)(ws);
    unsigned short* w2t = (unsigned short*)(ws + 294912);
    float* inv1 = (float*)(ws + 589824);
    float* sh1  = (float*)(ws + 590336);
    float* inv2 = (float*)(ws + 590848);
    float* sh2  = (float*)(ws + 591360);
    unsigned short* xh  = (unsigned short*)(ws + 591872);
    unsigned short* o1p = (unsigned short*)(ws + 17369088);

    prep_w<<<1152, 256, 0, stream>>>(w1, w2, w1t, w2t);
    bn_prep<<<1, 256, 0, stream>>>(g1, b1, m1, v1, g2, b2, m2, v2, inv1, sh1, inv2, sh2);
    nhwc_k<<<8192, 256, 0, stream>>>(x, xh);
    border_k<<<129, 256, 0, stream>>>(o1p);
    gemm1_k<<<512, 256, 0, stream>>>(xh, off, w1t, inv1, sh1, o1p);
    gemm2_k<<<512, 256, 0, stream>>>(o1p, w2t, x, inv2, sh2, outp);
}